// Round 8
// baseline (493.208 us; speedup 1.0000x reference)
//
#include <hip/hip_runtime.h>
#include <hip/hip_bf16.h>
#include <math.h>

// Problem constants: B=4, T=512, S=1024, H=768, V=50257
#define BB 4
#define TT 512
#define SS 1024
#define HH 768
#define VV 50257
#define NW 1571            // ceil(V/32) bitmap words per batch
#define NWP 1600           // padded stride for bm_g/pre_g
#define NPROJ 1536         // proj blocks (6144 rows / 4 waves)
#define NF4 25731584u      // (B*T*V)/4 float4s in logits
#define NWIN 25129u        // ceil(NF4/1024) 16KB windows
#define GRIDF 8192u        // fill grid

// ---------------------------------------------------------------------------
// Kernel P (fused prep, verified R7): blocks [0,1536) projections; blocks
// [1536,1540) per-batch bitmap/prefix/rank setup (+ zero the NWP padding).
// ---------------------------------------------------------------------------
__global__ __launch_bounds__(256) void prep_kernel(
    const float* __restrict__ src, const float* __restrict__ tgt,
    const float* __restrict__ W, const float* __restrict__ bptr,
    const int* __restrict__ ids,
    float* __restrict__ src_proj, float* __restrict__ tgt_proj,
    unsigned* __restrict__ bm_g, unsigned* __restrict__ pre_g,
    unsigned short* __restrict__ rank_g)
{
    __shared__ unsigned bm[NW];
    __shared__ unsigned pre[NW];
    __shared__ unsigned scan[256];
    const int tid = threadIdx.x;

    if (blockIdx.x < NPROJ) {
        const int wave = tid >> 6;
        const int lane = tid & 63;
        const int row  = blockIdx.x * 4 + wave;   // 0 .. 6143

        const float* vec;
        const float* w;
        if (row < BB * SS) { vec = src + (size_t)row * HH;            w = W; }
        else               { vec = tgt + (size_t)(row - BB*SS) * HH;  w = W + HH; }
        const float4* v4 = (const float4*)vec;
        const float4* w4 = (const float4*)w;

        float acc = 0.f;
#pragma unroll
        for (int k = 0; k < 3; ++k) {
            float4 a = v4[k * 64 + lane];
            float4 b = w4[k * 64 + lane];
            acc += a.x * b.x + a.y * b.y + a.z * b.z + a.w * b.w;
        }
#pragma unroll
        for (int off = 32; off > 0; off >>= 1) acc += __shfl_down(acc, off);
        if (lane == 0) {
            if (row < BB * SS) src_proj[row] = acc;
            else               tgt_proj[row - BB * SS] = acc + bptr[0];
        }
        return;
    }

    const int b = blockIdx.x - NPROJ;

    for (int i = tid; i < NW; i += 256) bm[i] = 0u;
    __syncthreads();
    const int* idb = ids + b * SS;
    for (int s = tid; s < SS; s += 256) {
        const int v = idb[s];
        atomicOr(&bm[v >> 5], 1u << (v & 31));
    }
    __syncthreads();

    unsigned cnt[7];
    unsigned local = 0;
    const int w0 = tid * 7;                 // 256*7 = 1792 >= 1571
#pragma unroll
    for (int k = 0; k < 7; ++k) {
        const int w = w0 + k;
        cnt[k] = local;
        local += (w < NW) ? (unsigned)__popc(bm[w]) : 0u;
    }
    scan[tid] = local;
    __syncthreads();
    for (int off = 1; off < 256; off <<= 1) {
        const unsigned mine = scan[tid];
        const unsigned add  = (tid >= off) ? scan[tid - off] : 0u;
        __syncthreads();
        scan[tid] = mine + add;
        __syncthreads();
    }
    const unsigned excl = (tid > 0) ? scan[tid - 1] : 0u;
#pragma unroll
    for (int k = 0; k < 7; ++k) {
        const int w = w0 + k;
        if (w < NW) {
            const unsigned p = excl + cnt[k];
            pre[w] = p;
            pre_g[b * NWP + w] = p;
            bm_g[b * NWP + w]  = bm[w];
        }
    }
    if (tid < NWP - NW) {                   // zero padding words
        bm_g[b * NWP + NW + tid]  = 0u;
        pre_g[b * NWP + NW + tid] = 0u;
    }
    __syncthreads();
    for (int s = tid; s < SS; s += 256) {
        const int v = idb[s];
        const unsigned w = (unsigned)v >> 5, bit = (unsigned)v & 31u;
        const unsigned r = pre[w] + (unsigned)__popc(bm[w] & ((1u << bit) - 1u));
        rank_g[b * SS + s] = (unsigned short)r;
    }
}

// ---------------------------------------------------------------------------
// Kernel V (verified R4): one block per (b,t) row. Dense per-row values
// vals_g[row][r] + fused p_gen.
// ---------------------------------------------------------------------------
__global__ __launch_bounds__(256) void vals_kernel(
    const float* __restrict__ attn,
    const float* __restrict__ src_proj,
    const float* __restrict__ tgt_proj,
    const unsigned short* __restrict__ rank_g,
    float* __restrict__ vals_g,           // [B*T, S]
    float* __restrict__ out)              // [B*T] p_gen
{
    __shared__ float vals[SS];
    __shared__ float wsum[4];
    const int row = blockIdx.x;
    const int b   = row >> 9;
    const int tid = threadIdx.x;

    ((float4*)vals)[tid] = make_float4(0.f, 0.f, 0.f, 0.f);
    __syncthreads();

    const float4*  a4p = (const float4*)(attn + (size_t)row * SS);
    const float4*  sp4 = (const float4*)(src_proj + b * SS);
    const ushort4* r4p = (const ushort4*)(rank_g + b * SS);
    const float4  a = a4p[tid];
    const float4  p = sp4[tid];
    const ushort4 r = r4p[tid];
    atomicAdd(&vals[r.x], a.x);
    atomicAdd(&vals[r.y], a.y);
    atomicAdd(&vals[r.z], a.z);
    atomicAdd(&vals[r.w], a.w);
    float acc = a.x * p.x + a.y * p.y + a.z * p.z + a.w * p.w;
#pragma unroll
    for (int off = 32; off > 0; off >>= 1) acc += __shfl_down(acc, off);
    if ((tid & 63) == 0) wsum[tid >> 6] = acc;
    __syncthreads();
    if (tid == 0) {
        const float x = wsum[0] + wsum[1] + wsum[2] + wsum[3] + tgt_proj[row];
        out[row] = 1.f / (1.f + expf(-x));
    }
    ((float4*)(vals_g + (size_t)row * SS))[tid] = ((const float4*)vals)[tid];
}

// ---------------------------------------------------------------------------
// Kernel F: address-ordered compact-front fill (the clean topology test).
// Unlike R4: full occupancy (8 blocks/CU), 4 INDEPENDENT float4 chains per
// thread per 16KB window (loads hoistable -> latency covered), coalesced
// 1KB wave-stores. bm/pre (25KB) and front-local vals (~640KB) stay L2-hot.
// ---------------------------------------------------------------------------
__device__ __forceinline__ float lutg(unsigned row, unsigned col,
                                      const unsigned* __restrict__ bm_g,
                                      const unsigned* __restrict__ pre_g,
                                      const float* __restrict__ vals_g)
{
    const unsigned b = row >> 9;
    const unsigned w = bm_g[b * NWP + (col >> 5)];
    const unsigned bit = col & 31u;
    if ((w >> bit) & 1u) {
        const unsigned r = pre_g[b * NWP + (col >> 5)]
                         + (unsigned)__popc(w & ((1u << bit) - 1u));
        return vals_g[(size_t)row * SS + r];
    }
    return 0.f;
}

__global__ __launch_bounds__(256) void fill_kernel(
    const unsigned* __restrict__ bm_g,
    const unsigned* __restrict__ pre_g,
    const float* __restrict__ vals_g,
    float* __restrict__ logits)           // [B*T*V], 16B-aligned
{
    const unsigned tid = threadIdx.x;
    float4* p4 = (float4*)logits;
    for (unsigned W = blockIdx.x; W < NWIN; W += GRIDF) {
#pragma unroll
        for (int k = 0; k < 4; ++k) {
            const unsigned f = W * 1024u + (unsigned)k * 256u + tid;
            if (f >= NF4) continue;
            const unsigned e   = f << 2;
            const unsigned row = e / VV;              // magic-mul division
            const unsigned col = e - row * VV;
            float4 o = make_float4(0.f, 0.f, 0.f, 0.f);
            if (col + 3u < VV) {                      // single-row fast path
                const unsigned base = (row >> 9) * NWP;
                const unsigned wi = col >> 5;
                const unsigned sh = col & 31u;
                const unsigned w0 = bm_g[base + wi];
                unsigned nib;
                if (sh <= 28u) {
                    nib = (w0 >> sh) & 0xFu;
                } else {                              // wi+1 < NWP (padded 0)
                    const unsigned w1 = bm_g[base + wi + 1u];
                    nib = ((w0 >> sh) | (w1 << (32u - sh))) & 0xFu;
                }
                if (nib) {
                    if (nib & 1u) o.x = lutg(row, col,      bm_g, pre_g, vals_g);
                    if (nib & 2u) o.y = lutg(row, col + 1u, bm_g, pre_g, vals_g);
                    if (nib & 4u) o.z = lutg(row, col + 2u, bm_g, pre_g, vals_g);
                    if (nib & 8u) o.w = lutg(row, col + 3u, bm_g, pre_g, vals_g);
                }
            } else {                                  // row-straddle (rare)
                float* oo = &o.x;
#pragma unroll
                for (int j = 0; j < 4; ++j) {
                    const unsigned re = (e + j) / VV;
                    const unsigned ce = (e + j) - re * VV;
                    oo[j] = lutg(re, ce, bm_g, pre_g, vals_g);
                }
            }
            p4[f] = o;
        }
    }
}

extern "C" void kernel_launch(void* const* d_in, const int* in_sizes, int n_in,
                              void* d_out, int out_size, void* d_ws, size_t ws_size,
                              hipStream_t stream) {
    const int*   ids  = (const int*)d_in[0];    // [B,S]
    const float* attn = (const float*)d_in[1];  // [B,T,S]
    const float* src  = (const float*)d_in[2];  // [B,S,H]
    const float* tgt  = (const float*)d_in[3];  // [B,T,H]
    const float* W    = (const float*)d_in[4];  // [2H,1]
    const float* bp   = (const float*)d_in[5];  // [1]

    float* out = (float*)d_out;                 // [B*T (p_gen) | B*T*V]

    // ws layout (all 16B-aligned)
    float*          src_proj = (float*)d_ws;                        // 4096 f
    float*          tgt_proj = src_proj + BB * SS;                  // 2048 f
    float*          vals_g   = tgt_proj + BB * TT;                  // 2M f (8 MB)
    unsigned*       bm_g     = (unsigned*)(vals_g + (size_t)BB*TT*SS); // B*NWP
    unsigned*       pre_g    = bm_g + BB * NWP;                     // B*NWP
    unsigned short* rank_g   = (unsigned short*)(pre_g + BB * NWP); // B*S u16

    prep_kernel<<<NPROJ + BB, 256, 0, stream>>>(
        src, tgt, W, bp, ids, src_proj, tgt_proj, bm_g, pre_g, rank_g);
    vals_kernel<<<BB * TT, 256, 0, stream>>>(
        attn, src_proj, tgt_proj, rank_g, vals_g, out);
    fill_kernel<<<GRIDF, 256, 0, stream>>>(
        bm_g, pre_g, vals_g, out + BB * TT);
}

// Round 9
// 462.526 us; speedup vs baseline: 1.0663x; 1.0663x over previous
//
#include <hip/hip_runtime.h>
#include <hip/hip_bf16.h>
#include <math.h>

// Problem constants: B=4, T=512, S=1024, H=768, V=50257
#define BB 4
#define TT 512
#define SS 1024
#define HH 768
#define VV 50257
#define NW 1571            // ceil(V/32) bitmap words per batch
#define NWP 1600           // padded stride for bm_g/pre_g
#define NPROJ 1536         // proj blocks (6144 rows / 4 waves)

// ---------------------------------------------------------------------------
// Kernel P (fused prep): blocks [0,1536) do projections; blocks [1536,1540)
// do per-batch bitmap/rank setup. Measured optimum (R7: 464 us).
// ---------------------------------------------------------------------------
__global__ __launch_bounds__(256) void prep_kernel(
    const float* __restrict__ src, const float* __restrict__ tgt,
    const float* __restrict__ W, const float* __restrict__ bptr,
    const int* __restrict__ ids,
    float* __restrict__ src_proj, float* __restrict__ tgt_proj,
    unsigned* __restrict__ bm_g, unsigned* __restrict__ pre_g,
    unsigned short* __restrict__ rank_g)
{
    __shared__ unsigned bm[NW];
    __shared__ unsigned pre[NW];
    __shared__ unsigned scan[256];
    const int tid = threadIdx.x;

    if (blockIdx.x < NPROJ) {
        // ---- projection role: one wave per row, 4 rows/block ----
        const int wave = tid >> 6;
        const int lane = tid & 63;
        const int row  = blockIdx.x * 4 + wave;   // 0 .. 6143

        const float* vec;
        const float* w;
        if (row < BB * SS) { vec = src + (size_t)row * HH;            w = W; }
        else               { vec = tgt + (size_t)(row - BB*SS) * HH;  w = W + HH; }
        const float4* v4 = (const float4*)vec;
        const float4* w4 = (const float4*)w;

        float acc = 0.f;
#pragma unroll
        for (int k = 0; k < 3; ++k) {
            float4 a = v4[k * 64 + lane];
            float4 b = w4[k * 64 + lane];
            acc += a.x * b.x + a.y * b.y + a.z * b.z + a.w * b.w;
        }
#pragma unroll
        for (int off = 32; off > 0; off >>= 1) acc += __shfl_down(acc, off);
        if (lane == 0) {
            if (row < BB * SS) src_proj[row] = acc;
            else               tgt_proj[row - BB * SS] = acc + bptr[0];
        }
        return;
    }

    // ---- setup role: one block per batch ----
    const int b = blockIdx.x - NPROJ;

    for (int i = tid; i < NW; i += 256) bm[i] = 0u;
    __syncthreads();
    const int* idb = ids + b * SS;
    for (int s = tid; s < SS; s += 256) {
        const int v = idb[s];
        atomicOr(&bm[v >> 5], 1u << (v & 31));
    }
    __syncthreads();

    unsigned cnt[7];
    unsigned local = 0;
    const int w0 = tid * 7;                 // 256*7 = 1792 >= 1571
#pragma unroll
    for (int k = 0; k < 7; ++k) {
        const int w = w0 + k;
        cnt[k] = local;
        local += (w < NW) ? (unsigned)__popc(bm[w]) : 0u;
    }
    scan[tid] = local;
    __syncthreads();
    for (int off = 1; off < 256; off <<= 1) {
        const unsigned mine = scan[tid];
        const unsigned add  = (tid >= off) ? scan[tid - off] : 0u;
        __syncthreads();
        scan[tid] = mine + add;
        __syncthreads();
    }
    const unsigned excl = (tid > 0) ? scan[tid - 1] : 0u;
#pragma unroll
    for (int k = 0; k < 7; ++k) {
        const int w = w0 + k;
        if (w < NW) {
            const unsigned p = excl + cnt[k];
            pre[w] = p;
            pre_g[b * NWP + w] = p;
            bm_g[b * NWP + w]  = bm[w];
        }
    }
    __syncthreads();
    for (int s = tid; s < SS; s += 256) {
        const int v = idb[s];
        const unsigned w = (unsigned)v >> 5, bit = (unsigned)v & 31u;
        const unsigned r = pre[w] + (unsigned)__popc(bm[w] & ((1u << bit) - 1u));
        rank_g[b * SS + s] = (unsigned short)r;
    }
}

__device__ __forceinline__ float lut1(int v, const unsigned* bm,
                                      const unsigned* pre, const float* vals)
{
    const unsigned w = bm[v >> 5];
    const unsigned bit = (unsigned)v & 31u;
    if ((w >> bit) & 1u)
        return vals[pre[v >> 5] + (unsigned)__popc(w & ((1u << bit) - 1u))];
    return 0.f;
}

// ---------------------------------------------------------------------------
// Kernel B: one block per (b,t) row. Single-touch streaming write, plain
// (L2-allocating) stores — measured fastest across all variants:
// instruction-mix (R2=R3), NT stores (+20), flat topology (+29..+80).
//   pass 1: vals[rank[s]] += attn[row,s] (LDS atomics, vectorized) + p_gen
//   pass 2: sweep the row; nibble-test LDS bitmap, substitute vals on hit.
// ---------------------------------------------------------------------------
__global__ __launch_bounds__(256) void row_kernel(
    const float* __restrict__ attn,
    const float* __restrict__ src_proj,
    const float* __restrict__ tgt_proj,
    const unsigned* __restrict__ bm_g,
    const unsigned* __restrict__ pre_g,
    const unsigned short* __restrict__ rank_g,
    float* __restrict__ out)
{
    __shared__ unsigned bm[NW];
    __shared__ unsigned pre[NW];
    __shared__ float vals[SS];
    __shared__ float wsum[4];

    const int row = blockIdx.x;     // 0 .. B*T-1
    const int b   = row >> 9;       // T = 512
    const int tid = threadIdx.x;

    for (int i = tid; i < NW; i += 256) { bm[i] = bm_g[b*NWP+i]; pre[i] = pre_g[b*NWP+i]; }
    ((float4*)vals)[tid] = make_float4(0.f, 0.f, 0.f, 0.f);
    __syncthreads();

    // ---- pass 1: vals accumulate + p_gen dot (1024 = 4*256, vectorized) ----
    const float4*  a4p = (const float4*)(attn + (size_t)row * SS);
    const float4*  sp4 = (const float4*)(src_proj + b * SS);
    const ushort4* r4p = (const ushort4*)(rank_g + b * SS);
    const float4  a = a4p[tid];
    const float4  p = sp4[tid];
    const ushort4 r = r4p[tid];
    atomicAdd(&vals[r.x], a.x);
    atomicAdd(&vals[r.y], a.y);
    atomicAdd(&vals[r.z], a.z);
    atomicAdd(&vals[r.w], a.w);
    float acc = a.x * p.x + a.y * p.y + a.z * p.z + a.w * p.w;
#pragma unroll
    for (int off = 32; off > 0; off >>= 1) acc += __shfl_down(acc, off);
    if ((tid & 63) == 0) wsum[tid >> 6] = acc;
    __syncthreads();   // vals final + wsum visible
    if (tid == 0) {
        const float x = wsum[0] + wsum[1] + wsum[2] + wsum[3] + tgt_proj[row];
        out[row] = 1.f / (1.f + expf(-x));
    }

    // ---- pass 2: single-touch streaming write ----
    float* logits = out + (BB * TT) + (size_t)row * VV;
    const int head = (int)(((16u - (unsigned)((uintptr_t)logits & 15u)) & 15u) >> 2);
    if (tid < head) logits[tid] = lut1(tid, bm, pre, vals);

    const int n4 = (VV - head) >> 2;
    float4* p4 = (float4*)(logits + head);
    for (int i = tid; i < n4; i += 256) {
        const int v0 = head + (i << 2);
        float4 o = make_float4(0.f, 0.f, 0.f, 0.f);
        const unsigned w  = bm[v0 >> 5];
        const unsigned sh = (unsigned)v0 & 31u;
        unsigned nib;
        if (sh <= 28u) {
            nib = (w >> sh) & 0xFu;
        } else {   // straddle: v0 <= V-4 keeps (v0>>5)+1 < NW
            const unsigned hi = bm[(v0 >> 5) + 1];
            nib = ((w >> sh) | (hi << (32u - sh))) & 0xFu;
        }
        if (nib) {
            o.x = lut1(v0,     bm, pre, vals);
            o.y = lut1(v0 + 1, bm, pre, vals);
            o.z = lut1(v0 + 2, bm, pre, vals);
            o.w = lut1(v0 + 3, bm, pre, vals);
        }
        p4[i] = o;
    }
    const int done = head + (n4 << 2);
    for (int v = done + tid; v < VV; v += 256)
        logits[v] = lut1(v, bm, pre, vals);
}

extern "C" void kernel_launch(void* const* d_in, const int* in_sizes, int n_in,
                              void* d_out, int out_size, void* d_ws, size_t ws_size,
                              hipStream_t stream) {
    const int*   ids  = (const int*)d_in[0];    // [B,S]
    const float* attn = (const float*)d_in[1];  // [B,T,S]
    const float* src  = (const float*)d_in[2];  // [B,S,H]
    const float* tgt  = (const float*)d_in[3];  // [B,T,H]
    const float* W    = (const float*)d_in[4];  // [2H,1]
    const float* bp   = (const float*)d_in[5];  // [1]

    float* out = (float*)d_out;                 // [B*T (p_gen) | B*T*V]

    // ws layout (all 16B-aligned)
    float*          src_proj = (float*)d_ws;                        // 4096 f
    float*          tgt_proj = src_proj + BB * SS;                  // 2048 f
    unsigned*       bm_g     = (unsigned*)(tgt_proj + BB * TT);     // B*NWP u32
    unsigned*       pre_g    = bm_g + BB * NWP;                     // B*NWP u32
    unsigned short* rank_g   = (unsigned short*)(pre_g + BB * NWP); // B*S u16

    prep_kernel<<<NPROJ + BB, 256, 0, stream>>>(
        src, tgt, W, bp, ids, src_proj, tgt_proj, bm_g, pre_g, rank_g);
    row_kernel<<<BB * TT, 256, 0, stream>>>(
        attn, src_proj, tgt_proj, bm_g, pre_g, rank_g, out);
}